// Round 11
// baseline (923.006 us; speedup 1.0000x reference)
//
#include <hip/hip_runtime.h>
#include <math.h>

typedef _Float16 f16;
typedef __fp16 h2 __attribute__((ext_vector_type(2)));
typedef f16 f16x8 __attribute__((ext_vector_type(8)));
typedef float f32x16 __attribute__((ext_vector_type(16)));

// ws layout (f16 units):
//  0..49152: w1,w2,w3 A-frags (pi-permuted k): [l][fb][ks][lane][i]
//  W0F 49152 (2048): [fb][lane][i], k=8g+i: k<9 -> w0 row k; k==9 -> b0 (bias row); else 0
//  W4F 51200 (4096): [ks][lane][i], rows ln<2 = w4 col ln (pi-permuted k), else 0
//  BIAS16 55296 (384): f16 bias for mid layers:
//    idx = (((lm*4+fb)*2+half)*2+g)*8 + i  -> b_{lm+1}[32fb + (i&3) + 8*(2*half+(i>>2)) + 4g]
// LDS: [0,49152) = w1-3 frags; [49152,49536) = BIAS16 copy. 99072 bytes.
#define LW0 0
#define LW1 16384
#define LW2 32768
#define W0F 49152
#define W4F 51200
#define BIAS16 55296
#define LBIAS 49152
#define LDS_F16 49536

__global__ void zero_f32(float* __restrict__ p, int n) {
    int i = blockIdx.x * blockDim.x + threadIdx.x;
    if (i < n) p[i] = 0.0f;
}

__global__ void prep_weights(const float* __restrict__ w1, const float* __restrict__ w2,
                             const float* __restrict__ w3, const float* __restrict__ w0,
                             const float* __restrict__ b0, const float* __restrict__ b1,
                             const float* __restrict__ b2, const float* __restrict__ b3,
                             const float* __restrict__ w4, f16* __restrict__ ws) {
    int t = blockIdx.x * 256 + threadIdx.x;
    if (t < 49152) {                     // w1,w2,w3 A-frags, pi-permuted k
        int l = t >> 14, rem = t & 16383;
        int fb = rem >> 12, ks = (rem >> 9) & 7, lane = (rem >> 3) & 63, i = rem & 7;
        int g = lane >> 5, ln = lane & 31;
        int F = 32 * (ks >> 1) + (i & 3) + 8 * (2 * (ks & 1) + (i >> 2)) + 4 * g;
        const float* w = (l == 0) ? w1 : (l == 1) ? w2 : w3;
        ws[t] = (f16)w[F * 128 + 32 * fb + ln];
    } else if (t < 51200) {              // w0 A-frags + bias row at k=9
        int rem = t - 49152;
        int fb = rem >> 9, lane = (rem >> 3) & 63, i = rem & 7;
        int g = lane >> 5, ln = lane & 31;
        int k = 8 * g + i;
        int f = 32 * fb + ln;
        float v = (k < 9) ? w0[k * 128 + f] : (k == 9 ? b0[f] : 0.0f);
        ws[t] = (f16)v;
    } else if (t < 55296) {              // w4 A-frags, pi-permuted k
        int rem = t - 51200;
        int ks = rem >> 9, lane = (rem >> 3) & 63, i = rem & 7;
        int g = lane >> 5, ln = lane & 31;
        int F = 32 * (ks >> 1) + (i & 3) + 8 * (2 * (ks & 1) + (i >> 2)) + 4 * g;
        ws[t] = (ln < 2) ? (f16)w4[F * 2 + ln] : (f16)0;
    } else if (t < 55680) {              // packed f16 mid-layer bias
        int m = t - 55296;
        int i = m & 7, g = (m >> 3) & 1, half = (m >> 4) & 1, fb = (m >> 5) & 3, lm = m >> 7;
        const float* bl = (lm == 0) ? b1 : (lm == 1) ? b2 : b3;
        ws[t] = (f16)bl[32 * fb + (i & 3) + 8 * (2 * half + (i >> 2)) + 4 * g];
    }
}

#define MF(w, b, c) __builtin_amdgcn_mfma_f32_32x32x16_f16(w, b, c, 0, 0, 0)

#define ZACC(acc) { _Pragma("unroll") for (int r_ = 0; r_ < 16; ++r_) acc[r_] = 0.0f; }

// plain ReLU+RTZ pack (layer 0: bias came through the k=9 MFMA row)
#define PACKB(dst, acc, b) {                                                   \
    h2 z2; z2[0] = (__fp16)0; z2[1] = (__fp16)0;                               \
    h2 p0 = __builtin_elementwise_max(__builtin_amdgcn_cvt_pkrtz(acc[8*(b)+0], acc[8*(b)+1]), z2); \
    h2 p1 = __builtin_elementwise_max(__builtin_amdgcn_cvt_pkrtz(acc[8*(b)+2], acc[8*(b)+3]), z2); \
    h2 p2 = __builtin_elementwise_max(__builtin_amdgcn_cvt_pkrtz(acc[8*(b)+4], acc[8*(b)+5]), z2); \
    h2 p3 = __builtin_elementwise_max(__builtin_amdgcn_cvt_pkrtz(acc[8*(b)+6], acc[8*(b)+7]), z2); \
    dst[0]=p0[0]; dst[1]=p0[1]; dst[2]=p1[0]; dst[3]=p1[1];                    \
    dst[4]=p2[0]; dst[5]=p2[1]; dst[6]=p3[0]; dst[7]=p3[1]; }

// pack with f16 bias add before ReLU (mid layers)
#define PACKBB(dst, acc, b, bias) {                                            \
    h2 z2; z2[0] = (__fp16)0; z2[1] = (__fp16)0;                               \
    const h2* bp_ = (const h2*)&(bias);                                        \
    h2 p0 = __builtin_elementwise_max(__builtin_amdgcn_cvt_pkrtz(acc[8*(b)+0], acc[8*(b)+1]) + bp_[0], z2); \
    h2 p1 = __builtin_elementwise_max(__builtin_amdgcn_cvt_pkrtz(acc[8*(b)+2], acc[8*(b)+3]) + bp_[1], z2); \
    h2 p2 = __builtin_elementwise_max(__builtin_amdgcn_cvt_pkrtz(acc[8*(b)+4], acc[8*(b)+5]) + bp_[2], z2); \
    h2 p3 = __builtin_elementwise_max(__builtin_amdgcn_cvt_pkrtz(acc[8*(b)+6], acc[8*(b)+7]) + bp_[3], z2); \
    dst[0]=p0[0]; dst[1]=p0[1]; dst[2]=p1[0]; dst[3]=p1[1];                    \
    dst[4]=p2[0]; dst[5]=p2[1]; dst[6]=p3[0]; dst[7]=p3[1]; }

#define MIDFB(LBASE, lm, fb, B0,B1,B2,B3,B4,B5,B6,B7, O0, O1) {                \
    f32x16 acc; ZACC(acc);                                                     \
    const f16* wb = lds + (LBASE) + (fb) * 4096 + lane * 8;                    \
    f16x8 w;                                                                   \
    w = *(const f16x8*)(wb + 0*512); acc = MF(w, B0, acc);                     \
    w = *(const f16x8*)(wb + 1*512); acc = MF(w, B1, acc);                     \
    w = *(const f16x8*)(wb + 2*512); acc = MF(w, B2, acc);                     \
    w = *(const f16x8*)(wb + 3*512); acc = MF(w, B3, acc);                     \
    w = *(const f16x8*)(wb + 4*512); acc = MF(w, B4, acc);                     \
    w = *(const f16x8*)(wb + 5*512); acc = MF(w, B5, acc);                     \
    w = *(const f16x8*)(wb + 6*512); acc = MF(w, B6, acc);                     \
    w = *(const f16x8*)(wb + 7*512); acc = MF(w, B7, acc);                     \
    f16x8 bb0 = lbv[((((lm)*4+(fb))*2+0)*2)+g];                                \
    f16x8 bb1 = lbv[((((lm)*4+(fb))*2+1)*2)+g];                                \
    PACKBB(O0, acc, 0, bb0); PACKBB(O1, acc, 1, bb1); }

#define MIDLAYER(LBASE, lm, I0,I1,I2,I3,I4,I5,I6,I7, O0,O1,O2,O3,O4,O5,O6,O7)  \
    MIDFB(LBASE, lm, 0, I0,I1,I2,I3,I4,I5,I6,I7, O0, O1);                      \
    MIDFB(LBASE, lm, 1, I0,I1,I2,I3,I4,I5,I6,I7, O2, O3);                      \
    MIDFB(LBASE, lm, 2, I0,I1,I2,I3,I4,I5,I6,I7, O4, O5);                      \
    MIDFB(LBASE, lm, 3, I0,I1,I2,I3,I4,I5,I6,I7, O6, O7);

#define L0FB(fb, O0, O1) {                                                     \
    f32x16 acc; ZACC(acc);                                                     \
    f16x8 w = w0gv[(fb) * 64 + lane];                                          \
    acc = MF(w, bh, acc); acc = MF(w, blo, acc);                               \
    PACKB(O0, acc, 0); PACKB(O1, acc, 1); }

__launch_bounds__(1024, 4)
__global__ void gnn_mfma(const float* __restrict__ pos, const float* __restrict__ vel,
                         const float* __restrict__ a, const float* __restrict__ vnorm,
                         const float* __restrict__ b4,
                         const int* __restrict__ ei, const int* __restrict__ did,
                         const f16* __restrict__ ws, float* __restrict__ out,
                         int nNodes, int nEdges)
{
    extern __shared__ __align__(16) f16 lds[];

    const int tid = threadIdx.x;
    const int lane = tid & 63;
    const int wid = tid >> 6;
    const int g = lane >> 5;
    const int c = lane & 31;

    // ---- stage w1-3 frags + packed bias into LDS ONCE per block lifetime ----
    {
        const f16x8* wv = (const f16x8*)ws;
        f16x8* lv = (f16x8*)lds;
        #pragma unroll
        for (int it = 0; it < 6; ++it) lv[it * 1024 + tid] = wv[it * 1024 + tid];
        if (tid < 48) lv[6144 + tid] = wv[6912 + tid];   // bias block
    }
    __syncthreads();

    const f16x8* w0gv = (const f16x8*)(ws + W0F);
    const f16x8* w4gv = (const f16x8*)(ws + W4F);
    const f16x8* lbv  = (const f16x8*)(lds + LBIAS);
    const float b40 = b4[0], b41 = b4[1];
    const float invn = 1.0f / vnorm[0];
    const float2* embp = (const float2*)(a + (size_t)did[0] * (size_t)nNodes * 2);

    const int nCh = (nEdges + 31) >> 5;
    #pragma unroll 1
    for (int chunk = blockIdx.x * 16 + wid; chunk < nCh; chunk += (gridDim.x << 4)) {
        // ---- gather: one edge per col, loads on g==0 half only ----
        float fx0=0,fx1=0,fx2=0,fx3=0,fx4=0,fx5=0,fx6=0,fx7=0,fx8=0;
        int dsti = 0;
        const int e = chunk * 32 + c;
        if (g == 0 && e < nEdges) {
            dsti = ei[e];
            int srci = ei[nEdges + e];
            float2 pd = ((const float2*)pos)[dsti];
            float2 ps = ((const float2*)pos)[srci];
            float2 vd = ((const float2*)vel)[dsti];
            float2 vs = ((const float2*)vel)[srci];
            float2 ae = embp[dsti];
            fx0 = (ps.x - pd.x) / 0.1f;
            fx1 = (ps.y - pd.y) / 0.1f;
            fx2 = sqrtf(fx0 * fx0 + fx1 * fx1);
            fx3 = vd.x * invn; fx4 = vd.y * invn;
            fx5 = vs.x * invn; fx6 = vs.y * invn;
            fx7 = ae.x; fx8 = ae.y;
        }
        float ay = __shfl(fx8, c);         // g==1 needs feat8 (k=8) of its col

        f16x8 bh, blo;
        #pragma unroll
        for (int i = 0; i < 8; ++i) { bh[i] = (f16)0; blo[i] = (f16)0; }
        if (g == 0) {
            f16 h;
            h=(f16)fx0; bh[0]=h; blo[0]=(f16)(fx0-(float)h);
            h=(f16)fx1; bh[1]=h; blo[1]=(f16)(fx1-(float)h);
            h=(f16)fx2; bh[2]=h; blo[2]=(f16)(fx2-(float)h);
            h=(f16)fx3; bh[3]=h; blo[3]=(f16)(fx3-(float)h);
            h=(f16)fx4; bh[4]=h; blo[4]=(f16)(fx4-(float)h);
            h=(f16)fx5; bh[5]=h; blo[5]=(f16)(fx5-(float)h);
            h=(f16)fx6; bh[6]=h; blo[6]=(f16)(fx6-(float)h);
            h=(f16)fx7; bh[7]=h; blo[7]=(f16)(fx7-(float)h);
        } else {
            f16 h = (f16)ay; bh[0] = h; blo[0] = (f16)(ay - (float)h);
            bh[1] = (f16)1.0f;             // k=9 bias row multiplier
        }

        // ---- MLP fully in registers; w1-3 streamed from LDS ----
        f16x8 Pa0,Pa1,Pa2,Pa3,Pa4,Pa5,Pa6,Pa7;
        f16x8 Pb0,Pb1,Pb2,Pb3,Pb4,Pb5,Pb6,Pb7;

        L0FB(0, Pa0, Pa1);  L0FB(1, Pa2, Pa3);  L0FB(2, Pa4, Pa5);  L0FB(3, Pa6, Pa7);

        MIDLAYER(LW0, 0, Pa0,Pa1,Pa2,Pa3,Pa4,Pa5,Pa6,Pa7, Pb0,Pb1,Pb2,Pb3,Pb4,Pb5,Pb6,Pb7)
        MIDLAYER(LW1, 1, Pb0,Pb1,Pb2,Pb3,Pb4,Pb5,Pb6,Pb7, Pa0,Pa1,Pa2,Pa3,Pa4,Pa5,Pa6,Pa7)
        MIDLAYER(LW2, 2, Pa0,Pa1,Pa2,Pa3,Pa4,Pa5,Pa6,Pa7, Pb0,Pb1,Pb2,Pb3,Pb4,Pb5,Pb6,Pb7)

        // ---- final layer 128 -> 2 (rows 0,1 of D), atomic segment-sum ----
        {
            f32x16 acc; ZACC(acc);
            if (g == 0) { acc[0] = b40; acc[1] = b41; }
            f16x8 w;
            w = w4gv[0*64 + lane]; acc = MF(w, Pb0, acc);
            w = w4gv[1*64 + lane]; acc = MF(w, Pb1, acc);
            w = w4gv[2*64 + lane]; acc = MF(w, Pb2, acc);
            w = w4gv[3*64 + lane]; acc = MF(w, Pb3, acc);
            w = w4gv[4*64 + lane]; acc = MF(w, Pb4, acc);
            w = w4gv[5*64 + lane]; acc = MF(w, Pb5, acc);
            w = w4gv[6*64 + lane]; acc = MF(w, Pb6, acc);
            w = w4gv[7*64 + lane]; acc = MF(w, Pb7, acc);
            if (g == 0 && e < nEdges) {
                atomicAdd(&out[2 * dsti],     acc[0]);
                atomicAdd(&out[2 * dsti + 1], acc[1]);
            }
        }
    }
}

extern "C" void kernel_launch(void* const* d_in, const int* in_sizes, int n_in,
                              void* d_out, int out_size, void* d_ws, size_t ws_size,
                              hipStream_t stream) {
    const float* pos   = (const float*)d_in[0];
    const float* vel   = (const float*)d_in[1];
    const float* a     = (const float*)d_in[2];
    const float* vnorm = (const float*)d_in[3];
    const float* w0    = (const float*)d_in[4];
    const float* b0    = (const float*)d_in[5];
    const float* w1    = (const float*)d_in[6];
    const float* b1    = (const float*)d_in[7];
    const float* w2    = (const float*)d_in[8];
    const float* b2    = (const float*)d_in[9];
    const float* w3    = (const float*)d_in[10];
    const float* b3    = (const float*)d_in[11];
    const float* w4    = (const float*)d_in[12];
    const float* b4    = (const float*)d_in[13];
    const int*   ei    = (const int*)d_in[14];
    const int*   did   = (const int*)d_in[15];
    float* out = (float*)d_out;
    f16* ws = (f16*)d_ws;

    int nEdges = in_sizes[14] / 2;   // 800000
    int nNodes = in_sizes[0] / 2;    // 50000

    hipFuncSetAttribute((const void*)gnn_mfma,
                        hipFuncAttributeMaxDynamicSharedMemorySize, LDS_F16 * 2);

    hipLaunchKernelGGL(zero_f32, dim3((out_size + 255) / 256), dim3(256), 0, stream,
                       out, out_size);
    hipLaunchKernelGGL(prep_weights, dim3(218), dim3(256), 0, stream,
                       w1, w2, w3, w0, b0, b1, b2, b3, w4, ws);
    hipLaunchKernelGGL(gnn_mfma, dim3(256), dim3(1024), LDS_F16 * 2, stream,
                       pos, vel, a, vnorm, b4, ei, did, ws, out,
                       nNodes, nEdges);
}

// Round 12
// 113.613 us; speedup vs baseline: 8.1241x; 8.1241x over previous
//
#include <hip/hip_runtime.h>
#include <math.h>

typedef _Float16 f16;
typedef __fp16 h2 __attribute__((ext_vector_type(2)));
typedef f16 f16x8 __attribute__((ext_vector_type(8)));
typedef float f32x16 __attribute__((ext_vector_type(16)));

// ws layout (f16 units):
//  0..49152: w1,w2,w3 A-frags (pi-permuted k): [l][fb][ks][lane][i]
//  W0F 49152 (2048): [fb][lane][i], k=8g+i: k<9 -> w0 row k; k==9 -> b0; else 0
//  W4F 51200 (4096): [ks][lane][i], rows ln<2 = w4 col ln (pi-permuted k), else 0
//  BIAS16 55296 (384): f16 mid-layer bias:
//    idx = (((lm*4+fb)*2+half)*2+g)*8 + i -> b_{lm+1}[32fb + (i&3) + 8*(2*half+(i>>2)) + 4g]
// LDS (static): [0,49152) = w1-3 frags; [49152,49536) = bias. 99072 B.
#define LW0 0
#define LW1 16384
#define LW2 32768
#define W0F 49152
#define W4F 51200
#define BIAS16 55296
#define LBIAS 49152
#define LDS_F16 49536

__global__ void zero_f32(float* __restrict__ p, int n) {
    int i = blockIdx.x * blockDim.x + threadIdx.x;
    if (i < n) p[i] = 0.0f;
}

__global__ void prep_weights(const float* __restrict__ w1, const float* __restrict__ w2,
                             const float* __restrict__ w3, const float* __restrict__ w0,
                             const float* __restrict__ b0, const float* __restrict__ b1,
                             const float* __restrict__ b2, const float* __restrict__ b3,
                             const float* __restrict__ w4, f16* __restrict__ ws) {
    int t = blockIdx.x * 256 + threadIdx.x;
    if (t < 49152) {                     // w1,w2,w3 A-frags, pi-permuted k
        int l = t >> 14, rem = t & 16383;
        int fb = rem >> 12, ks = (rem >> 9) & 7, lane = (rem >> 3) & 63, i = rem & 7;
        int g = lane >> 5, ln = lane & 31;
        int F = 32 * (ks >> 1) + (i & 3) + 8 * (2 * (ks & 1) + (i >> 2)) + 4 * g;
        const float* w = (l == 0) ? w1 : (l == 1) ? w2 : w3;
        ws[t] = (f16)w[F * 128 + 32 * fb + ln];
    } else if (t < 51200) {              // w0 A-frags + b0 row at k=9
        int rem = t - 49152;
        int fb = rem >> 9, lane = (rem >> 3) & 63, i = rem & 7;
        int g = lane >> 5, ln = lane & 31;
        int k = 8 * g + i;
        int f = 32 * fb + ln;
        float v = (k < 9) ? w0[k * 128 + f] : (k == 9 ? b0[f] : 0.0f);
        ws[t] = (f16)v;
    } else if (t < 55296) {              // w4 A-frags, pi-permuted k
        int rem = t - 51200;
        int ks = rem >> 9, lane = (rem >> 3) & 63, i = rem & 7;
        int g = lane >> 5, ln = lane & 31;
        int F = 32 * (ks >> 1) + (i & 3) + 8 * (2 * (ks & 1) + (i >> 2)) + 4 * g;
        ws[t] = (ln < 2) ? (f16)w4[F * 2 + ln] : (f16)0;
    } else if (t < 55680) {              // packed f16 mid-layer bias
        int m = t - 55296;
        int i = m & 7, g = (m >> 3) & 1, half = (m >> 4) & 1, fb = (m >> 5) & 3, lm = m >> 7;
        const float* bl = (lm == 0) ? b1 : (lm == 1) ? b2 : b3;
        ws[t] = (f16)bl[32 * fb + (i & 3) + 8 * (2 * half + (i >> 2)) + 4 * g];
    }
}

#define MF(w, b, c) __builtin_amdgcn_mfma_f32_32x32x16_f16(w, b, c, 0, 0, 0)

#define ZACC(acc) { _Pragma("unroll") for (int r_ = 0; r_ < 16; ++r_) acc[r_] = 0.0f; }

// plain ReLU+RTZ pack (layer 0: bias came through the k=9 row)
#define PACKB(dst, acc, b) {                                                   \
    h2 z2; z2[0] = (__fp16)0; z2[1] = (__fp16)0;                               \
    h2 p0 = __builtin_elementwise_max(__builtin_amdgcn_cvt_pkrtz(acc[8*(b)+0], acc[8*(b)+1]), z2); \
    h2 p1 = __builtin_elementwise_max(__builtin_amdgcn_cvt_pkrtz(acc[8*(b)+2], acc[8*(b)+3]), z2); \
    h2 p2 = __builtin_elementwise_max(__builtin_amdgcn_cvt_pkrtz(acc[8*(b)+4], acc[8*(b)+5]), z2); \
    h2 p3 = __builtin_elementwise_max(__builtin_amdgcn_cvt_pkrtz(acc[8*(b)+6], acc[8*(b)+7]), z2); \
    dst[0]=p0[0]; dst[1]=p0[1]; dst[2]=p1[0]; dst[3]=p1[1];                    \
    dst[4]=p2[0]; dst[5]=p2[1]; dst[6]=p3[0]; dst[7]=p3[1]; }

// pack with f16 bias add before ReLU (mid layers)
#define PACKBB(dst, acc, b, bias) {                                            \
    h2 z2; z2[0] = (__fp16)0; z2[1] = (__fp16)0;                               \
    const h2* bp_ = (const h2*)&(bias);                                        \
    h2 p0 = __builtin_elementwise_max(__builtin_amdgcn_cvt_pkrtz(acc[8*(b)+0], acc[8*(b)+1]) + bp_[0], z2); \
    h2 p1 = __builtin_elementwise_max(__builtin_amdgcn_cvt_pkrtz(acc[8*(b)+2], acc[8*(b)+3]) + bp_[1], z2); \
    h2 p2 = __builtin_elementwise_max(__builtin_amdgcn_cvt_pkrtz(acc[8*(b)+4], acc[8*(b)+5]) + bp_[2], z2); \
    h2 p3 = __builtin_elementwise_max(__builtin_amdgcn_cvt_pkrtz(acc[8*(b)+6], acc[8*(b)+7]) + bp_[3], z2); \
    dst[0]=p0[0]; dst[1]=p0[1]; dst[2]=p1[0]; dst[3]=p1[1];                    \
    dst[4]=p2[0]; dst[5]=p2[1]; dst[6]=p3[0]; dst[7]=p3[1]; }

#define MIDFB(LBASE, lm, fb, B0,B1,B2,B3,B4,B5,B6,B7, O0, O1) {                \
    f32x16 acc; ZACC(acc);                                                     \
    const f16* wb = lds + (LBASE) + (fb) * 4096 + lane * 8;                    \
    f16x8 w;                                                                   \
    w = *(const f16x8*)(wb + 0*512); acc = MF(w, B0, acc);                     \
    w = *(const f16x8*)(wb + 1*512); acc = MF(w, B1, acc);                     \
    w = *(const f16x8*)(wb + 2*512); acc = MF(w, B2, acc);                     \
    w = *(const f16x8*)(wb + 3*512); acc = MF(w, B3, acc);                     \
    w = *(const f16x8*)(wb + 4*512); acc = MF(w, B4, acc);                     \
    w = *(const f16x8*)(wb + 5*512); acc = MF(w, B5, acc);                     \
    w = *(const f16x8*)(wb + 6*512); acc = MF(w, B6, acc);                     \
    w = *(const f16x8*)(wb + 7*512); acc = MF(w, B7, acc);                     \
    f16x8 bb0 = lbv[((((lm)*4+(fb))*2+0)*2)+g];                                \
    f16x8 bb1 = lbv[((((lm)*4+(fb))*2+1)*2)+g];                                \
    PACKBB(O0, acc, 0, bb0); PACKBB(O1, acc, 1, bb1); }

#define MIDLAYER(LBASE, lm, I0,I1,I2,I3,I4,I5,I6,I7, O0,O1,O2,O3,O4,O5,O6,O7)  \
    MIDFB(LBASE, lm, 0, I0,I1,I2,I3,I4,I5,I6,I7, O0, O1);                      \
    MIDFB(LBASE, lm, 1, I0,I1,I2,I3,I4,I5,I6,I7, O2, O3);                      \
    MIDFB(LBASE, lm, 2, I0,I1,I2,I3,I4,I5,I6,I7, O4, O5);                      \
    MIDFB(LBASE, lm, 3, I0,I1,I2,I3,I4,I5,I6,I7, O6, O7);

#define L0FB(fb, O0, O1) {                                                     \
    f32x16 acc; ZACC(acc);                                                     \
    f16x8 w = w0gv[(fb) * 64 + lane];                                          \
    acc = MF(w, bh, acc); acc = MF(w, blo, acc);                               \
    PACKB(O0, acc, 0); PACKB(O1, acc, 1); }

__launch_bounds__(1024, 4)
__global__ void gnn_mfma(const float* __restrict__ pos, const float* __restrict__ vel,
                         const float* __restrict__ a, const float* __restrict__ vnorm,
                         const float* __restrict__ b4,
                         const int* __restrict__ ei, const int* __restrict__ did,
                         const f16* __restrict__ ws, float* __restrict__ out,
                         int nNodes, int nEdges)
{
    __shared__ __align__(16) f16 lds[LDS_F16];   // static: honest occupancy model

    const int tid = threadIdx.x;
    const int lane = tid & 63;
    const int wid = tid >> 6;
    const int g = lane >> 5;
    const int c = lane & 31;

    // ---- stage w1-3 frags + packed bias into LDS (one barrier) ----
    {
        const f16x8* wv = (const f16x8*)ws;
        f16x8* lv = (f16x8*)lds;
        #pragma unroll
        for (int it = 0; it < 6; ++it) lv[it * 1024 + tid] = wv[it * 1024 + tid];
        if (tid < 48) lv[6144 + tid] = wv[6912 + tid];   // bias block
    }
    __syncthreads();

    const int chunk = blockIdx.x * 16 + wid;
    if (chunk >= ((nEdges + 31) >> 5)) return;

    const f16x8* w0gv = (const f16x8*)(ws + W0F);
    const f16x8* w4gv = (const f16x8*)(ws + W4F);
    const f16x8* lbv  = (const f16x8*)(lds + LBIAS);

    // ---- gather: one edge per col, loads on g==0 half only ----
    float fx0=0,fx1=0,fx2=0,fx3=0,fx4=0,fx5=0,fx6=0,fx7=0,fx8=0;
    int dsti = 0;
    const int e = chunk * 32 + c;
    if (g == 0 && e < nEdges) {
        dsti = ei[e];
        int srci = ei[nEdges + e];
        float2 pd = ((const float2*)pos)[dsti];
        float2 ps = ((const float2*)pos)[srci];
        float2 vd = ((const float2*)vel)[dsti];
        float2 vs = ((const float2*)vel)[srci];
        const float2* embp = (const float2*)(a + (size_t)did[0] * (size_t)nNodes * 2);
        float2 ae = embp[dsti];
        float invn = 1.0f / vnorm[0];
        fx0 = (ps.x - pd.x) / 0.1f;
        fx1 = (ps.y - pd.y) / 0.1f;
        fx2 = sqrtf(fx0 * fx0 + fx1 * fx1);
        fx3 = vd.x * invn; fx4 = vd.y * invn;
        fx5 = vs.x * invn; fx6 = vs.y * invn;
        fx7 = ae.x; fx8 = ae.y;
    }
    float ay = __shfl(fx8, c);             // g==1 needs feat8 (k=8) of its col

    f16x8 bh, blo;
    #pragma unroll
    for (int i = 0; i < 8; ++i) { bh[i] = (f16)0; blo[i] = (f16)0; }
    if (g == 0) {
        f16 h;
        h=(f16)fx0; bh[0]=h; blo[0]=(f16)(fx0-(float)h);
        h=(f16)fx1; bh[1]=h; blo[1]=(f16)(fx1-(float)h);
        h=(f16)fx2; bh[2]=h; blo[2]=(f16)(fx2-(float)h);
        h=(f16)fx3; bh[3]=h; blo[3]=(f16)(fx3-(float)h);
        h=(f16)fx4; bh[4]=h; blo[4]=(f16)(fx4-(float)h);
        h=(f16)fx5; bh[5]=h; blo[5]=(f16)(fx5-(float)h);
        h=(f16)fx6; bh[6]=h; blo[6]=(f16)(fx6-(float)h);
        h=(f16)fx7; bh[7]=h; blo[7]=(f16)(fx7-(float)h);
    } else {
        f16 h = (f16)ay; bh[0] = h; blo[0] = (f16)(ay - (float)h);
        bh[1] = (f16)1.0f;                 // k=9 bias-row multiplier
    }

    // ---- MLP fully in registers; w1-3 streamed from LDS, w0/w4 from L2 ----
    f16x8 Pa0,Pa1,Pa2,Pa3,Pa4,Pa5,Pa6,Pa7;
    f16x8 Pb0,Pb1,Pb2,Pb3,Pb4,Pb5,Pb6,Pb7;

    L0FB(0, Pa0, Pa1);  L0FB(1, Pa2, Pa3);  L0FB(2, Pa4, Pa5);  L0FB(3, Pa6, Pa7);

    MIDLAYER(LW0, 0, Pa0,Pa1,Pa2,Pa3,Pa4,Pa5,Pa6,Pa7, Pb0,Pb1,Pb2,Pb3,Pb4,Pb5,Pb6,Pb7)
    MIDLAYER(LW1, 1, Pb0,Pb1,Pb2,Pb3,Pb4,Pb5,Pb6,Pb7, Pa0,Pa1,Pa2,Pa3,Pa4,Pa5,Pa6,Pa7)
    MIDLAYER(LW2, 2, Pa0,Pa1,Pa2,Pa3,Pa4,Pa5,Pa6,Pa7, Pb0,Pb1,Pb2,Pb3,Pb4,Pb5,Pb6,Pb7)

    // ---- final layer 128 -> 2 (rows 0,1 of D), atomic segment-sum ----
    {
        f32x16 acc; ZACC(acc);
        if (g == 0) { acc[0] = b4[0]; acc[1] = b4[1]; }
        f16x8 w;
        w = w4gv[0*64 + lane]; acc = MF(w, Pb0, acc);
        w = w4gv[1*64 + lane]; acc = MF(w, Pb1, acc);
        w = w4gv[2*64 + lane]; acc = MF(w, Pb2, acc);
        w = w4gv[3*64 + lane]; acc = MF(w, Pb3, acc);
        w = w4gv[4*64 + lane]; acc = MF(w, Pb4, acc);
        w = w4gv[5*64 + lane]; acc = MF(w, Pb5, acc);
        w = w4gv[6*64 + lane]; acc = MF(w, Pb6, acc);
        w = w4gv[7*64 + lane]; acc = MF(w, Pb7, acc);
        if (g == 0 && e < nEdges) {
            atomicAdd(&out[2 * dsti],     acc[0]);
            atomicAdd(&out[2 * dsti + 1], acc[1]);
        }
    }
}

extern "C" void kernel_launch(void* const* d_in, const int* in_sizes, int n_in,
                              void* d_out, int out_size, void* d_ws, size_t ws_size,
                              hipStream_t stream) {
    const float* pos   = (const float*)d_in[0];
    const float* vel   = (const float*)d_in[1];
    const float* a     = (const float*)d_in[2];
    const float* vnorm = (const float*)d_in[3];
    const float* w0    = (const float*)d_in[4];
    const float* b0    = (const float*)d_in[5];
    const float* w1    = (const float*)d_in[6];
    const float* b1    = (const float*)d_in[7];
    const float* w2    = (const float*)d_in[8];
    const float* b2    = (const float*)d_in[9];
    const float* w3    = (const float*)d_in[10];
    const float* b3    = (const float*)d_in[11];
    const float* w4    = (const float*)d_in[12];
    const float* b4    = (const float*)d_in[13];
    const int*   ei    = (const int*)d_in[14];
    const int*   did   = (const int*)d_in[15];
    float* out = (float*)d_out;
    f16* ws = (f16*)d_ws;

    int nEdges = in_sizes[14] / 2;   // 800000
    int nNodes = in_sizes[0] / 2;    // 50000

    hipLaunchKernelGGL(zero_f32, dim3((out_size + 255) / 256), dim3(256), 0, stream,
                       out, out_size);
    hipLaunchKernelGGL(prep_weights, dim3(218), dim3(256), 0, stream,
                       w1, w2, w3, w0, b0, b1, b2, b3, w4, ws);
    int nChunks = (nEdges + 31) / 32;             // 25000
    int grid = (nChunks + 15) / 16;               // 1563 blocks of 16 waves
    hipLaunchKernelGGL(gnn_mfma, dim3(grid), dim3(1024), 0, stream,
                       pos, vel, a, vnorm, b4, ei, did, ws, out,
                       nNodes, nEdges);
}